// Round 7
// baseline (7117.114 us; speedup 1.0000x reference)
//
#include <hip/hip_runtime.h>
#include <math.h>

#define N 1024
#define NN (N*N)

// ---------- wave argmax over (val, key): max val, tie -> min key ----------
__device__ __forceinline__ void wave_argmax_kv(float& v, int& k) {
  #pragma unroll
  for (int off = 32; off > 0; off >>= 1) {
    float ov = __shfl_down(v, off);
    int   ok = __shfl_down(k, off);
    if (ov > v || (ov == v && ok < k)) { v = ov; k = ok; }
  }
}

// ======================= init =======================
__global__ void init_kernel(double* scores) {
  int t = threadIdx.x;
  if (t < 16) scores[t] = 0.0;
}

// ======================= copy x -> LU workspace =======================
__global__ __launch_bounds__(256) void copy_kernel(const float4* __restrict__ src,
                                                   float4* __restrict__ dst) {
  int i = blockIdx.x * 256 + threadIdx.x;   // grid sized exactly: 16M floats / 4
  dst[i] = src[i];
}

// ======================= LU panel (width 32): 256 thr x 4 register rows =========
// Latency-shaped rebuild of the VERIFIED R5/R6 panel: same pivot semantics,
// same key packing (pos<<11)|orig (max |v|, tie -> min pos), same posOf/lay
// simulation and ipiv output -> bitwise-identical LU/scores/ipiv. Changes are
// purely scheduling: 4 waves instead of 16 (cheaper barriers), intra-thread
// argmax over 4 register rows, and the cross-wave combine is 4 INDEPENDENT
// LDS loads + register tree instead of a 15-deep dependent scan.
__global__ __launch_bounds__(256, 1) void panel_kernel(float* __restrict__ lu,
                                                       int* __restrict__ ipiv,
                                                       double* __restrict__ scores,
                                                       int c0) {
  __shared__ __align__(16) float bufP[32];
  __shared__ float ujjS[32];
  __shared__ float redv[4];
  __shared__ int   redk[4];
  __shared__ int   posOf[1024];
  __shared__ int   lay[1024];
  const int m = blockIdx.x;
  float* A = lu + (size_t)m * NN;
  const int R = N - c0;
  const int tid = threadIdx.x;
  const int s0 = tid, s1 = tid + 256, s2 = tid + 512, s3 = tid + 768;
  bool a0 = s0 < R, a1 = s1 < R, a2 = s2 < R, a3 = s3 < R;
  float r0[32], r1[32], r2[32], r3[32];

  // ---- load owned rows (cols c0..c0+31, 16B aligned; c0 % 32 == 0) ----
  if (a0) { const float4* g = (const float4*)(A + (size_t)(c0 + s0) * N + c0);
    #pragma unroll
    for (int q = 0; q < 8; ++q) { float4 v = g[q]; r0[4*q]=v.x; r0[4*q+1]=v.y; r0[4*q+2]=v.z; r0[4*q+3]=v.w; } }
  if (a1) { const float4* g = (const float4*)(A + (size_t)(c0 + s1) * N + c0);
    #pragma unroll
    for (int q = 0; q < 8; ++q) { float4 v = g[q]; r1[4*q]=v.x; r1[4*q+1]=v.y; r1[4*q+2]=v.z; r1[4*q+3]=v.w; } }
  if (a2) { const float4* g = (const float4*)(A + (size_t)(c0 + s2) * N + c0);
    #pragma unroll
    for (int q = 0; q < 8; ++q) { float4 v = g[q]; r2[4*q]=v.x; r2[4*q+1]=v.y; r2[4*q+2]=v.z; r2[4*q+3]=v.w; } }
  if (a3) { const float4* g = (const float4*)(A + (size_t)(c0 + s3) * N + c0);
    #pragma unroll
    for (int q = 0; q < 8; ++q) { float4 v = g[q]; r3[4*q]=v.x; r3[4*q+1]=v.y; r3[4*q+2]=v.z; r3[4*q+3]=v.w; } }
  for (int i = tid; i < 1024; i += 256) { posOf[i] = i; lay[i] = i; }
  __syncthreads();

  // ---- pre-scan: pivot for column 0 (pos == orig initially) ----
  int worig;
  {
    float val = -1.0f; int key = 0x7fffffff;
    if (a0) { float v = fabsf(r0[0]); int k = (s0 << 11) | s0; if (v > val || (v == val && k < key)) { val = v; key = k; } }
    if (a1) { float v = fabsf(r1[0]); int k = (s1 << 11) | s1; if (v > val || (v == val && k < key)) { val = v; key = k; } }
    if (a2) { float v = fabsf(r2[0]); int k = (s2 << 11) | s2; if (v > val || (v == val && k < key)) { val = v; key = k; } }
    if (a3) { float v = fabsf(r3[0]); int k = (s3 << 11) | s3; if (v > val || (v == val && k < key)) { val = v; key = k; } }
    wave_argmax_kv(val, key);
    if ((tid & 63) == 0) { redv[tid >> 6] = val; redk[tid >> 6] = key; }
    __syncthreads();
    float bv = redv[0]; int bk = redk[0];
    float v1 = redv[1]; int k1 = redk[1];
    float v2 = redv[2]; int k2 = redk[2];
    float v3 = redv[3]; int k3 = redk[3];
    if (v1 > bv || (v1 == bv && k1 < bk)) { bv = v1; bk = k1; }
    if (v2 > bv || (v2 == bv && k2 < bk)) { bv = v2; bk = k2; }
    if (v3 > bv || (v3 == bv && k3 < bk)) { bv = v3; bk = k3; }
    worig = bk & 0x7FF;
  }

  #pragma unroll
  for (int j = 0; j < 32; ++j) {
    // ---- publish pivot row, retire in place ----
    if (s0 == worig) { a0 = false;
      #pragma unroll
      for (int q = 0; q < 8; ++q) *(float4*)&bufP[4*q] = make_float4(r0[4*q], r0[4*q+1], r0[4*q+2], r0[4*q+3]); }
    if (s1 == worig) { a1 = false;
      #pragma unroll
      for (int q = 0; q < 8; ++q) *(float4*)&bufP[4*q] = make_float4(r1[4*q], r1[4*q+1], r1[4*q+2], r1[4*q+3]); }
    if (s2 == worig) { a2 = false;
      #pragma unroll
      for (int q = 0; q < 8; ++q) *(float4*)&bufP[4*q] = make_float4(r2[4*q], r2[4*q+1], r2[4*q+2], r2[4*q+3]); }
    if (s3 == worig) { a3 = false;
      #pragma unroll
      for (int q = 0; q < 8; ++q) *(float4*)&bufP[4*q] = make_float4(r3[4*q], r3[4*q+1], r3[4*q+2], r3[4*q+3]); }
    if (tid == 0) {       // LAPACK swap simulation (positions only)
      int p = posOf[worig];
      ipiv[m * 32 + j] = c0 + p;
      int a = lay[j];
      lay[j] = worig; lay[p] = a;
      posOf[worig] = j; posOf[a] = p;
    }
    __syncthreads();      // B1: bufP + posOf(step j) visible

    // U-row j into registers (only quads covering cols >= j); broadcast reads
    float u[32];
    #pragma unroll
    for (int q = 0; q < 8; ++q) {
      if (4*q + 3 >= j) {
        float4 v = *(const float4*)&bufP[4*q];
        u[4*q] = v.x; u[4*q+1] = v.y; u[4*q+2] = v.z; u[4*q+3] = v.w;
      }
    }
    if (tid == 0) ujjS[j] = u[j];
    const float rujj = 1.0f / u[j];

    float l0 = 0.f, l1 = 0.f, l2 = 0.f, l3 = 0.f;
    if (a0) { l0 = r0[j] * rujj; r0[j] = l0; }
    if (a1) { l1 = r1[j] * rujj; r1[j] = l1; }
    if (a2) { l2 = r2[j] * rujj; r2[j] = l2; }
    if (a3) { l3 = r3[j] * rujj; r3[j] = l3; }

    if (j < 31) {
      // positions AFTER this step's swap (posOf updated before B1)
      int p0 = posOf[s0], p1 = posOf[s1], p2 = posOf[s2], p3 = posOf[s3];
      float val = -1.0f; int key = 0x7fffffff;
      // peeled col j+1: update + fused scan; then remaining cols
      if (a0) { float v = r0[j+1] - l0 * u[j+1]; r0[j+1] = v;
        float av = fabsf(v); int k = (p0 << 11) | s0;
        if (av > val || (av == val && k < key)) { val = av; key = k; } }
      if (a1) { float v = r1[j+1] - l1 * u[j+1]; r1[j+1] = v;
        float av = fabsf(v); int k = (p1 << 11) | s1;
        if (av > val || (av == val && k < key)) { val = av; key = k; } }
      if (a2) { float v = r2[j+1] - l2 * u[j+1]; r2[j+1] = v;
        float av = fabsf(v); int k = (p2 << 11) | s2;
        if (av > val || (av == val && k < key)) { val = av; key = k; } }
      if (a3) { float v = r3[j+1] - l3 * u[j+1]; r3[j+1] = v;
        float av = fabsf(v); int k = (p3 << 11) | s3;
        if (av > val || (av == val && k < key)) { val = av; key = k; } }
      #pragma unroll
      for (int jj = j + 2; jj < 32; ++jj) {
        if (a0) r0[jj] -= l0 * u[jj];
        if (a1) r1[jj] -= l1 * u[jj];
        if (a2) r2[jj] -= l2 * u[jj];
        if (a3) r3[jj] -= l3 * u[jj];
      }
      wave_argmax_kv(val, key);
      if ((tid & 63) == 0) { redv[tid >> 6] = val; redk[tid >> 6] = key; }
    }
    __syncthreads();      // B2: redv/redk complete; bufP/posOf reads done
    if (j < 31) {
      float bv = redv[0]; int bk = redk[0];
      float v1 = redv[1]; int k1 = redk[1];
      float v2 = redv[2]; int k2 = redk[2];
      float v3 = redv[3]; int k3 = redk[3];
      if (v1 > bv || (v1 == bv && k1 < bk)) { bv = v1; bk = k1; }
      if (v2 > bv || (v2 == bv && k2 < bk)) { bv = v2; bk = k2; }
      if (v3 > bv || (v3 == bv && k3 < bk)) { bv = v3; bk = k3; }
      worig = bk & 0x7FF;
    }
  }

  // ---- writeback: each row to its final LAPACK position ----
  if (s0 < R) { int fp = posOf[s0]; float4* g = (float4*)(A + (size_t)(c0 + fp) * N + c0);
    #pragma unroll
    for (int q = 0; q < 8; ++q) g[q] = make_float4(r0[4*q], r0[4*q+1], r0[4*q+2], r0[4*q+3]); }
  if (s1 < R) { int fp = posOf[s1]; float4* g = (float4*)(A + (size_t)(c0 + fp) * N + c0);
    #pragma unroll
    for (int q = 0; q < 8; ++q) g[q] = make_float4(r1[4*q], r1[4*q+1], r1[4*q+2], r1[4*q+3]); }
  if (s2 < R) { int fp = posOf[s2]; float4* g = (float4*)(A + (size_t)(c0 + fp) * N + c0);
    #pragma unroll
    for (int q = 0; q < 8; ++q) g[q] = make_float4(r2[4*q], r2[4*q+1], r2[4*q+2], r2[4*q+3]); }
  if (s3 < R) { int fp = posOf[s3]; float4* g = (float4*)(A + (size_t)(c0 + fp) * N + c0);
    #pragma unroll
    for (int q = 0; q < 8; ++q) g[q] = make_float4(r3[4*q], r3[4*q+1], r3[4*q+2], r3[4*q+3]); }
  if (tid == 0) {
    double logsum = 0.0;
    #pragma unroll 1
    for (int j = 0; j < 32; ++j) logsum += log(fabs((double)ujjS[j]));
    atomicAdd(&scores[m], logsum);
  }
}

// ======================= permutation-gather + TRSM =======================
// VERIFIED round-6 kernel, unchanged.
__global__ __launch_bounds__(256) void ptrsm_kernel(float* __restrict__ lu,
                                                    const int* __restrict__ ipiv,
                                                    int c0, int ncs) {
  const int m  = blockIdx.x / ncs;
  const int cs = blockIdx.x % ncs;
  const int s0 = c0 + 32 + cs * 256;
  const int tid = threadIdx.x;
  const int col = s0 + tid;
  const bool ac = col < N;
  float* A = lu + (size_t)m * NN;
  const int R = N - c0;
  __shared__ int   rowAt[1024];     // content map over rows [c0, N)
  __shared__ float L11s[32][33];
  __shared__ int   dDst[48];
  __shared__ int   dSrc[48];
  __shared__ int   dcount;

  for (int r = tid; r < R; r += 256) rowAt[r] = c0 + r;
  if (tid == 0) dcount = 0;
  for (int idx = tid; idx < 1024; idx += 256) {
    int i = idx >> 5, k = idx & 31;
    L11s[i][k] = A[(size_t)(c0 + i) * N + c0 + k];
  }
  __syncthreads();
  if (tid == 0) {
    #pragma unroll 1
    for (int j = 0; j < 32; ++j) {
      int p = ipiv[m * 32 + j];
      if (p != c0 + j) { int t = rowAt[j]; rowAt[j] = rowAt[p - c0]; rowAt[p - c0] = t; }
    }
  }
  __syncthreads();
  // collect displaced A22 rows (dst receives content of src)
  for (int r = 32 + tid; r < R; r += 256) {
    if (rowAt[r] != c0 + r) {
      int i = atomicAdd(&dcount, 1);
      dDst[i] = c0 + r; dSrc[i] = rowAt[r];
    }
  }
  __syncthreads();
  const int nd = dcount;   // <= 32

  // ---- read phase (all loads before any store) ----
  float pay[32];
  #pragma unroll
  for (int i = 0; i < 32; ++i)
    if (i < nd && ac) pay[i] = A[(size_t)dSrc[i] * N + col];
  float u[32];
  #pragma unroll
  for (int i = 0; i < 32; ++i)
    if (ac) u[i] = A[(size_t)rowAt[i] * N + col];

  // ---- TRSM: u = L11^{-1} a12 (unit diag) ----
  #pragma unroll
  for (int i = 1; i < 32; ++i) {
    float a = u[i];
    #pragma unroll
    for (int k = 0; k < 32; ++k)
      if (k < i) a -= L11s[i][k] * u[k];
    u[i] = a;
  }

  // ---- write phase ----
  #pragma unroll
  for (int i = 0; i < 32; ++i)
    if (i < nd && ac) A[(size_t)dDst[i] * N + col] = pay[i];
  #pragma unroll
  for (int i = 0; i < 32; ++i)
    if (ac) A[(size_t)(c0 + i) * N + col] = u[i];
}

// ======================= trailing update: A22 -= L21 @ U12 (K=32) ================
// VERIFIED round-6 kernel, unchanged.
__global__ __launch_bounds__(256) void update_kernel(float* __restrict__ lu,
                                                     int c0, int nrt, int ncs) {
  const int per = nrt * ncs;
  const int m  = blockIdx.x / per;
  const int t  = blockIdx.x % per;
  const int rt = t / ncs, cs = t % ncs;
  const int r0 = c0 + 32 + rt * 64;
  const int s0 = c0 + 32 + cs * 256;
  const int tid = threadIdx.x;
  float* A = lu + (size_t)m * NN;
  __shared__ float Lts[32][68];    // L21 tile transposed: [k][r]
  __shared__ float Us[32][260];    // U12 stripe: [k][c]
  for (int idx = tid; idx < 2048; idx += 256) {
    int r = idx >> 5, k = idx & 31;
    Lts[k][r] = (r0 + r < N) ? A[(size_t)(r0 + r) * N + c0 + k] : 0.0f;
  }
  for (int idx = tid; idx < 8192; idx += 256) {
    int k = idx >> 8, c = idx & 255;
    Us[k][c] = (s0 + c < N) ? A[(size_t)(c0 + k) * N + s0 + c] : 0.0f;
  }
  __syncthreads();
  const int tx = tid & 63;    // col group: 4 cols
  const int ty = tid >> 6;    // row group: 16 rows (== wave id -> uniform a-reads)
  float4 acc[16];
  #pragma unroll
  for (int e = 0; e < 16; ++e) acc[e] = make_float4(0.f, 0.f, 0.f, 0.f);
  #pragma unroll 4
  for (int k = 0; k < 32; ++k) {
    float4 b  = *(const float4*)&Us[k][tx * 4];
    float4 a0 = *(const float4*)&Lts[k][ty * 16 + 0];
    float4 a1 = *(const float4*)&Lts[k][ty * 16 + 4];
    float4 a2 = *(const float4*)&Lts[k][ty * 16 + 8];
    float4 a3 = *(const float4*)&Lts[k][ty * 16 + 12];
    acc[0].x  += a0.x*b.x; acc[0].y  += a0.x*b.y; acc[0].z  += a0.x*b.z; acc[0].w  += a0.x*b.w;
    acc[1].x  += a0.y*b.x; acc[1].y  += a0.y*b.y; acc[1].z  += a0.y*b.z; acc[1].w  += a0.y*b.w;
    acc[2].x  += a0.z*b.x; acc[2].y  += a0.z*b.y; acc[2].z  += a0.z*b.z; acc[2].w  += a0.z*b.w;
    acc[3].x  += a0.w*b.x; acc[3].y  += a0.w*b.y; acc[3].z  += a0.w*b.z; acc[3].w  += a0.w*b.w;
    acc[4].x  += a1.x*b.x; acc[4].y  += a1.x*b.y; acc[4].z  += a1.x*b.z; acc[4].w  += a1.x*b.w;
    acc[5].x  += a1.y*b.x; acc[5].y  += a1.y*b.y; acc[5].z  += a1.y*b.z; acc[5].w  += a1.y*b.w;
    acc[6].x  += a1.z*b.x; acc[6].y  += a1.z*b.y; acc[6].z  += a1.z*b.z; acc[6].w  += a1.z*b.w;
    acc[7].x  += a1.w*b.x; acc[7].y  += a1.w*b.y; acc[7].z  += a1.w*b.z; acc[7].w  += a1.w*b.w;
    acc[8].x  += a2.x*b.x; acc[8].y  += a2.x*b.y; acc[8].z  += a2.x*b.z; acc[8].w  += a2.x*b.w;
    acc[9].x  += a2.y*b.x; acc[9].y  += a2.y*b.y; acc[9].z  += a2.y*b.z; acc[9].w  += a2.y*b.w;
    acc[10].x += a2.z*b.x; acc[10].y += a2.z*b.y; acc[10].z += a2.z*b.z; acc[10].w += a2.z*b.w;
    acc[11].x += a2.w*b.x; acc[11].y += a2.w*b.y; acc[11].z += a2.w*b.z; acc[11].w += a2.w*b.w;
    acc[12].x += a3.x*b.x; acc[12].y += a3.x*b.y; acc[12].z += a3.x*b.z; acc[12].w += a3.x*b.w;
    acc[13].x += a3.y*b.x; acc[13].y += a3.y*b.y; acc[13].z += a3.y*b.z; acc[13].w += a3.y*b.w;
    acc[14].x += a3.z*b.x; acc[14].y += a3.z*b.y; acc[14].z += a3.z*b.z; acc[14].w += a3.z*b.w;
    acc[15].x += a3.w*b.x; acc[15].y += a3.w*b.y; acc[15].z += a3.w*b.z; acc[15].w += a3.w*b.w;
  }
  const bool colok = (s0 + tx * 4) < N;
  #pragma unroll
  for (int e = 0; e < 16; ++e) {
    int r = r0 + ty * 16 + e;
    if (r < N && colok) {
      float4* p = (float4*)&A[(size_t)r * N + s0 + tx * 4];
      float4 v = *p;
      v.x -= acc[e].x; v.y -= acc[e].y; v.z -= acc[e].z; v.w -= acc[e].w;
      *p = v;
    }
  }
}

// ======================= gate + top-k + effective weights =======================
__global__ void select_kernel(const void* __restrict__ flagsraw, const double* __restrict__ scores,
                              const float* __restrict__ w1, const float* __restrict__ b1,
                              const float* __restrict__ w2, const float* __restrict__ b2,
                              int* __restrict__ topidx, float* __restrict__ misc,
                              float* __restrict__ out_tail) {
  if (threadIdx.x != 0 || blockIdx.x != 0) return;
  const unsigned char* fb = (const unsigned char*)flagsraw;
  bool nonbin = false, off4 = false;
  for (int i = 0; i < 16; ++i) {
    if (fb[i] > 1) nonbin = true;
    if ((i & 3) && fb[i]) off4 = true;
  }
  int f[16]; int nact = 0;
  for (int i = 0; i < 16; ++i) {
    int v;
    if (nonbin)      v = (((const float*)flagsraw)[i] != 0.0f);
    else if (off4)   v = (fb[i] != 0);
    else             v = (((const int*)flagsraw)[i] != 0);
    f[i] = v; nact += v;
  }
  int gate = (nact >= 4) ? 1 : 0;   // THRESH = 4
  double sc[16];
  for (int i = 0; i < 16; ++i) sc[i] = f[i] ? scores[i] : -1.0e300;
  bool used[16] = {};
  for (int k = 0; k < 8; ++k) {     // descending, ties -> lowest index (lax.top_k)
    int bi = -1; double bv = 0.0;
    for (int i = 0; i < 16; ++i)
      if (!used[i] && (bi < 0 || sc[i] > bv)) { bv = sc[i]; bi = i; }
    used[bi] = true;
    topidx[k] = bi;
  }
  for (int cC = 0; cC < 10; ++cC) {
    float s = 0.0f;
    for (int h = 0; h < 32; ++h) s += w2[h] * w1[h * 10 + cC];
    misc[cC] = s;
  }
  float be = 0.0f;
  for (int h = 0; h < 32; ++h) be += w2[h] * b1[h];
  be += b2[0];
  misc[10] = be;
  ((int*)misc)[12] = gate;
  *out_tail = gate ? 1.0f : 0.0f;
}

// ======================= build combined right-hand matrices M0..M2 =======================
__global__ __launch_bounds__(256) void build_m_kernel(const float* __restrict__ x,
                                                      const int* __restrict__ topidx,
                                                      const float* __restrict__ misc,
                                                      float* __restrict__ M) {
  int i = blockIdx.x * 256 + threadIdx.x;   // 262144 float4 positions
  const float4* T1 = (const float4*)(x + (size_t)topidx[1] * NN);
  const float4* T2 = (const float4*)(x + (size_t)topidx[2] * NN);
  const float4* T3 = (const float4*)(x + (size_t)topidx[3] * NN);
  float w0 = misc[0], w1_ = misc[1], w2_ = misc[2], w3_ = misc[3], w4_ = misc[4], w5_ = misc[5];
  float4 t1 = T1[i], t2 = T2[i], t3 = T3[i];
  float4 m0, m1, m2;
  m0.x = w0 * t1.x + w1_ * t2.x + w2_ * t3.x;
  m0.y = w0 * t1.y + w1_ * t2.y + w2_ * t3.y;
  m0.z = w0 * t1.z + w1_ * t2.z + w2_ * t3.z;
  m0.w = w0 * t1.w + w1_ * t2.w + w2_ * t3.w;
  m1.x = w3_ * t2.x + w4_ * t3.x;
  m1.y = w3_ * t2.y + w4_ * t3.y;
  m1.z = w3_ * t2.z + w4_ * t3.z;
  m1.w = w3_ * t2.w + w4_ * t3.w;
  m2.x = w5_ * t3.x;  m2.y = w5_ * t3.y;  m2.z = w5_ * t3.z;  m2.w = w5_ * t3.w;
  ((float4*)M)[i] = m0;
  ((float4*)(M + NN))[i] = m1;
  ((float4*)(M + 2 * (size_t)NN))[i] = m2;
}

// ======================= split-K final GEMM: P[chunk] = A_chunk @ B_chunk ==========
// VERIFIED round-3 kernel, unchanged.
__global__ __launch_bounds__(256) void final_gemm_kernel(const float* __restrict__ x,
                                                         const float* __restrict__ M,
                                                         const int* __restrict__ topidx,
                                                         float* __restrict__ P) {
  const int chunk = blockIdx.x >> 8;   // 0..5
  const int t  = blockIdx.x & 255;
  const int tr = t >> 4, tc = t & 15;
  const int mi  = chunk >> 1;
  const int k0b = (chunk & 1) << 9;    // 0 or 512
  const float* A = x + (size_t)topidx[mi] * NN;
  const float* B = M + (size_t)mi * NN;
  __shared__ float As[32][68];   // A^T fragment: As[k][r], float4-aligned stride
  __shared__ float Bs[32][68];
  const int ty = threadIdx.x >> 4, tx = threadIdx.x & 15;
  float acc[4][4] = {};
  for (int k0 = k0b; k0 < k0b + 512; k0 += 32) {
    for (int idx = threadIdx.x; idx < 2048; idx += 256) {
      int r = idx >> 5, k = idx & 31;
      As[k][r] = A[(size_t)(tr * 64 + r) * N + k0 + k];
    }
    for (int idx = threadIdx.x; idx < 2048; idx += 256) {
      int k = idx >> 6, cc = idx & 63;
      Bs[k][cc] = B[(size_t)(k0 + k) * N + tc * 64 + cc];
    }
    __syncthreads();
    #pragma unroll 8
    for (int k = 0; k < 32; ++k) {
      float4 a = *(const float4*)&As[k][ty * 4];
      float4 b = *(const float4*)&Bs[k][tx * 4];
      acc[0][0] += a.x * b.x; acc[0][1] += a.x * b.y; acc[0][2] += a.x * b.z; acc[0][3] += a.x * b.w;
      acc[1][0] += a.y * b.x; acc[1][1] += a.y * b.y; acc[1][2] += a.y * b.z; acc[1][3] += a.y * b.w;
      acc[2][0] += a.z * b.x; acc[2][1] += a.z * b.y; acc[2][2] += a.z * b.z; acc[2][3] += a.z * b.w;
      acc[3][0] += a.w * b.x; acc[3][1] += a.w * b.y; acc[3][2] += a.w * b.z; acc[3][3] += a.w * b.w;
    }
    __syncthreads();
  }
  float* Pc = P + (size_t)chunk * NN;
  #pragma unroll
  for (int i = 0; i < 4; ++i) {
    size_t r = (size_t)(tr * 64 + ty * 4 + i);
    float4 v = make_float4(acc[i][0], acc[i][1], acc[i][2], acc[i][3]);
    *(float4*)&Pc[r * N + tc * 64 + tx * 4] = v;
  }
}

// ======================= reduce partials + preserve channels + bias ================
__global__ __launch_bounds__(256) void reduce_out_kernel(const float* __restrict__ x,
                                                         const float* __restrict__ P,
                                                         const int* __restrict__ topidx,
                                                         const float* __restrict__ misc,
                                                         float* __restrict__ out) {
  int i = blockIdx.x * 256 + threadIdx.x;   // 262144 float4 positions
  int gate = ((const int*)misc)[12];
  float4* o = (float4*)out;
  if (!gate) { o[i] = make_float4(0.f, 0.f, 0.f, 0.f); return; }
  float w6 = misc[6], w7 = misc[7], w8 = misc[8], w9 = misc[9], be = misc[10];
  float4 p0 = ((const float4*)(x + (size_t)topidx[4] * NN))[i];
  float4 p1 = ((const float4*)(x + (size_t)topidx[5] * NN))[i];
  float4 p2 = ((const float4*)(x + (size_t)topidx[6] * NN))[i];
  float4 p3 = ((const float4*)(x + (size_t)topidx[7] * NN))[i];
  float4 r;
  r.x = be + w6 * p0.x + w7 * p1.x + w8 * p2.x + w9 * p3.x;
  r.y = be + w6 * p0.y + w7 * p1.y + w8 * p2.y + w9 * p3.y;
  r.z = be + w6 * p0.z + w7 * p1.z + w8 * p2.z + w9 * p3.z;
  r.w = be + w6 * p0.w + w7 * p1.w + w8 * p2.w + w9 * p3.w;
  #pragma unroll
  for (int cN = 0; cN < 6; ++cN) {
    float4 q = ((const float4*)(P + (size_t)cN * NN))[i];
    r.x += q.x; r.y += q.y; r.z += q.z; r.w += q.w;
  }
  o[i] = r;
}

// ======================= host =======================
extern "C" void kernel_launch(void* const* d_in, const int* in_sizes, int n_in,
                              void* d_out, int out_size, void* d_ws, size_t ws_size,
                              hipStream_t stream) {
  const float* x  = (const float*)d_in[0];
  const void*  fl = d_in[1];
  const float* w1 = (const float*)d_in[2];
  const float* b1 = (const float*)d_in[3];
  const float* w2 = (const float*)d_in[4];
  const float* b2 = (const float*)d_in[5];
  float* out = (float*)d_out;

  char* ws = (char*)d_ws;
  float* LU = (float*)ws;                                // 64 MB (dead after LU phase)
  float* Mm = (float*)ws;                                // 12 MB, reuses LU space
  float* P  = (float*)(ws + (size_t)12 * 1024 * 1024);   // 24 MB partials, inside old LU
  size_t tail = (size_t)16 * NN * sizeof(float);         // 67,108,864
  double* scores = (double*)(ws + tail);                 // 16 doubles
  int*    ipiv   = (int*)(ws + tail + 256);              // 16*32 ints
  int*    topidx = (int*)(ws + tail + 256 + 2304);       // 8 ints
  float*  misc   = (float*)(ws + tail + 256 + 2304 + 256); // weff[10], beff, gate

  init_kernel<<<1, 64, 0, stream>>>(scores);
  copy_kernel<<<16384, 256, 0, stream>>>((const float4*)x, (float4*)LU);

  for (int c0 = 0; c0 < N; c0 += 32) {
    panel_kernel<<<16, 256, 0, stream>>>(LU, ipiv, scores, c0);
    int tcols = N - c0 - 32;
    if (tcols > 0) {
      int ncs = (tcols + 255) / 256;
      ptrsm_kernel<<<16 * ncs, 256, 0, stream>>>(LU, ipiv, c0, ncs);
      int nrt = (tcols + 63) / 64;
      update_kernel<<<16 * nrt * ncs, 256, 0, stream>>>(LU, c0, nrt, ncs);
    }
  }

  select_kernel<<<1, 64, 0, stream>>>(fl, scores, w1, b1, w2, b2, topidx, misc, out + NN);
  build_m_kernel<<<1024, 256, 0, stream>>>(x, topidx, misc, Mm);
  final_gemm_kernel<<<1536, 256, 0, stream>>>(x, Mm, topidx, P);
  reduce_out_kernel<<<1024, 256, 0, stream>>>(x, P, topidx, misc, out);
}

// Round 8
// 5038.173 us; speedup vs baseline: 1.4126x; 1.4126x over previous
//
#include <hip/hip_runtime.h>
#include <math.h>

#define N 1024
#define NN (N*N)
#define PST 36   // panel row stride in floats: 144B = 16B-aligned, bank-optimal

// ======================= init =======================
__global__ void init_kernel(double* scores) {
  int t = threadIdx.x;
  if (t < 16) scores[t] = 0.0;
}

// ======================= copy x -> LU workspace =======================
__global__ __launch_bounds__(256) void copy_kernel(const float4* __restrict__ src,
                                                   float4* __restrict__ dst) {
  int i = blockIdx.x * 256 + threadIdx.x;   // grid sized exactly: 16M floats / 4
  dst[i] = src[i];
}

// ======================= LU panel (width 32): SINGLE-WAVE, zero barriers =========
// One wave (64 lanes) per matrix. Panel rows in LDS row-major (stride 36 floats:
// 16B-aligned b128, 8 lanes per 4-bank span = minimal LDS contention). Cyclic row
// ownership (lane, lane+64, ...). Physical row swaps in LDS (8 lanes x b128) ->
// exact R1/R3 LAPACK pivot semantics: argmax |col j|, tie -> lowest row index;
// ipiv[j] = c0 + current pivot row. Next-column pivot scan fused into the rank-1
// update (verified R4+). Cross-lane reduction = shfl_xor butterfly (no LDS, no
// barrier); __syncthreads() on a 1-wave block is a near-free ordering fence.
__global__ __launch_bounds__(64, 1) void panel_kernel(float* __restrict__ lu,
                                                      int* __restrict__ ipiv,
                                                      double* __restrict__ scores,
                                                      int c0) {
  __shared__ __align__(16) float sh[1024 * PST];   // 147,456 B
  __shared__ float ujjS[32];
  const int m = blockIdx.x;
  float* A = lu + (size_t)m * NN;
  const int R = N - c0;
  const int lane = threadIdx.x;

  // ---- load panel rows (cols c0..c0+31 are 16B aligned; c0 % 32 == 0) ----
  for (int r = lane; r < R; r += 64) {
    const float4* g = (const float4*)(A + (size_t)(c0 + r) * N + c0);
    float* d = &sh[r * PST];
    #pragma unroll
    for (int q = 0; q < 8; ++q) *(float4*)&d[4 * q] = g[q];
  }
  __syncthreads();

  // ---- prescan: pivot for column 0 ----
  int pcur;
  {
    float bval = -1.0f; int brow = 0x7fffffff;
    for (int r = lane; r < R; r += 64) {
      float v = fabsf(sh[r * PST]);
      if (v > bval) { bval = v; brow = r; }   // ascending r -> tie keeps min r
    }
    #pragma unroll
    for (int mask = 32; mask; mask >>= 1) {
      float ov = __shfl_xor(bval, mask);
      int   orr = __shfl_xor(brow, mask);
      if (ov > bval || (ov == bval && orr < brow)) { bval = ov; brow = orr; }
    }
    pcur = brow;
  }

  #pragma unroll
  for (int j = 0; j < 32; ++j) {
    // ---- swap rows j <-> pcur in LDS (full 32-col rows, lanes 0..7) ----
    if (pcur != j && lane < 8) {
      float4 a = *(float4*)&sh[j * PST + 4 * lane];
      float4 b = *(float4*)&sh[pcur * PST + 4 * lane];
      *(float4*)&sh[j * PST + 4 * lane] = b;
      *(float4*)&sh[pcur * PST + 4 * lane] = a;
    }
    if (lane == 0) ipiv[m * 32 + j] = c0 + pcur;
    __syncthreads();   // swap visible (1-wave: ordering fence only)

    const float ujj = sh[j * PST + j];
    if (lane == 0) ujjS[j] = ujj;
    const float rujj = 1.0f / ujj;

    // U row j chunks into registers (broadcast reads; only chunks covering c>=j)
    float4 u4[8];
    #pragma unroll
    for (int q = 0; q < 8; ++q)
      if (4 * q + 3 >= j) u4[q] = *(const float4*)&sh[j * PST + 4 * q];

    // ---- scale L col + rank-1 update + fused scan of col j+1 ----
    float bval = -1.0f; int brow = 0x7fffffff;
    for (int r = lane; r < R; r += 64) {
      if (r <= j) continue;
      float* rp = &sh[r * PST];
      float l = 0.0f;
      float nv = 0.0f;
      #pragma unroll
      for (int q = 0; q < 8; ++q) {
        if (4 * q + 3 < j) continue;          // chunk entirely in finished L region
        float4 v = *(float4*)&rp[4 * q];
        #pragma unroll
        for (int e = 0; e < 4; ++e) {
          const int c = 4 * q + e;            // all constants after unroll
          float* pv = (&v.x) + e;
          const float uu = (&u4[q].x)[e];
          if (c == j)      { l = (*pv) * rujj; *pv = l; }
          else if (c > j)  { *pv -= l * uu; if (c == j + 1) nv = *pv; }
        }
        *(float4*)&rp[4 * q] = v;
      }
      if (j < 31) {
        float av = fabsf(nv);
        if (av > bval) { bval = av; brow = r; }  // ascending r -> min-r tie-break
      }
    }
    if (j < 31) {
      #pragma unroll
      for (int mask = 32; mask; mask >>= 1) {
        float ov = __shfl_xor(bval, mask);
        int   orr = __shfl_xor(brow, mask);
        if (ov > bval || (ov == bval && orr < brow)) { bval = ov; brow = orr; }
      }
      pcur = brow;
    }
    __syncthreads();   // updates visible before next swap
  }

  // ---- writeback ----
  for (int r = lane; r < R; r += 64) {
    float4* g = (float4*)(A + (size_t)(c0 + r) * N + c0);
    const float* s = &sh[r * PST];
    #pragma unroll
    for (int q = 0; q < 8; ++q) g[q] = *(const float4*)&s[4 * q];
  }
  // ---- logsum: lane-parallel logs + shfl-reduce ----
  double lg = 0.0;
  if (lane < 32) lg = log(fabs((double)ujjS[lane]));
  #pragma unroll
  for (int mask = 32; mask; mask >>= 1) lg += __shfl_xor(lg, mask);
  if (lane == 0) atomicAdd(&scores[m], lg);
}

// ======================= permutation-gather + TRSM =======================
// VERIFIED round-6 kernel, unchanged.
__global__ __launch_bounds__(256) void ptrsm_kernel(float* __restrict__ lu,
                                                    const int* __restrict__ ipiv,
                                                    int c0, int ncs) {
  const int m  = blockIdx.x / ncs;
  const int cs = blockIdx.x % ncs;
  const int s0 = c0 + 32 + cs * 256;
  const int tid = threadIdx.x;
  const int col = s0 + tid;
  const bool ac = col < N;
  float* A = lu + (size_t)m * NN;
  const int R = N - c0;
  __shared__ int   rowAt[1024];     // content map over rows [c0, N)
  __shared__ float L11s[32][33];
  __shared__ int   dDst[48];
  __shared__ int   dSrc[48];
  __shared__ int   dcount;

  for (int r = tid; r < R; r += 256) rowAt[r] = c0 + r;
  if (tid == 0) dcount = 0;
  for (int idx = tid; idx < 1024; idx += 256) {
    int i = idx >> 5, k = idx & 31;
    L11s[i][k] = A[(size_t)(c0 + i) * N + c0 + k];
  }
  __syncthreads();
  if (tid == 0) {
    #pragma unroll 1
    for (int j = 0; j < 32; ++j) {
      int p = ipiv[m * 32 + j];
      if (p != c0 + j) { int t = rowAt[j]; rowAt[j] = rowAt[p - c0]; rowAt[p - c0] = t; }
    }
  }
  __syncthreads();
  // collect displaced A22 rows (dst receives content of src)
  for (int r = 32 + tid; r < R; r += 256) {
    if (rowAt[r] != c0 + r) {
      int i = atomicAdd(&dcount, 1);
      dDst[i] = c0 + r; dSrc[i] = rowAt[r];
    }
  }
  __syncthreads();
  const int nd = dcount;   // <= 32

  // ---- read phase (all loads before any store) ----
  float pay[32];
  #pragma unroll
  for (int i = 0; i < 32; ++i)
    if (i < nd && ac) pay[i] = A[(size_t)dSrc[i] * N + col];
  float u[32];
  #pragma unroll
  for (int i = 0; i < 32; ++i)
    if (ac) u[i] = A[(size_t)rowAt[i] * N + col];

  // ---- TRSM: u = L11^{-1} a12 (unit diag) ----
  #pragma unroll
  for (int i = 1; i < 32; ++i) {
    float a = u[i];
    #pragma unroll
    for (int k = 0; k < 32; ++k)
      if (k < i) a -= L11s[i][k] * u[k];
    u[i] = a;
  }

  // ---- write phase ----
  #pragma unroll
  for (int i = 0; i < 32; ++i)
    if (i < nd && ac) A[(size_t)dDst[i] * N + col] = pay[i];
  #pragma unroll
  for (int i = 0; i < 32; ++i)
    if (ac) A[(size_t)(c0 + i) * N + col] = u[i];
}

// ======================= trailing update: A22 -= L21 @ U12 (K=32) ================
// VERIFIED round-6 kernel, unchanged.
__global__ __launch_bounds__(256) void update_kernel(float* __restrict__ lu,
                                                     int c0, int nrt, int ncs) {
  const int per = nrt * ncs;
  const int m  = blockIdx.x / per;
  const int t  = blockIdx.x % per;
  const int rt = t / ncs, cs = t % ncs;
  const int r0 = c0 + 32 + rt * 64;
  const int s0 = c0 + 32 + cs * 256;
  const int tid = threadIdx.x;
  float* A = lu + (size_t)m * NN;
  __shared__ float Lts[32][68];    // L21 tile transposed: [k][r]
  __shared__ float Us[32][260];    // U12 stripe: [k][c]
  for (int idx = tid; idx < 2048; idx += 256) {
    int r = idx >> 5, k = idx & 31;
    Lts[k][r] = (r0 + r < N) ? A[(size_t)(r0 + r) * N + c0 + k] : 0.0f;
  }
  for (int idx = tid; idx < 8192; idx += 256) {
    int k = idx >> 8, c = idx & 255;
    Us[k][c] = (s0 + c < N) ? A[(size_t)(c0 + k) * N + s0 + c] : 0.0f;
  }
  __syncthreads();
  const int tx = tid & 63;    // col group: 4 cols
  const int ty = tid >> 6;    // row group: 16 rows (== wave id -> uniform a-reads)
  float4 acc[16];
  #pragma unroll
  for (int e = 0; e < 16; ++e) acc[e] = make_float4(0.f, 0.f, 0.f, 0.f);
  #pragma unroll 4
  for (int k = 0; k < 32; ++k) {
    float4 b  = *(const float4*)&Us[k][tx * 4];
    float4 a0 = *(const float4*)&Lts[k][ty * 16 + 0];
    float4 a1 = *(const float4*)&Lts[k][ty * 16 + 4];
    float4 a2 = *(const float4*)&Lts[k][ty * 16 + 8];
    float4 a3 = *(const float4*)&Lts[k][ty * 16 + 12];
    acc[0].x  += a0.x*b.x; acc[0].y  += a0.x*b.y; acc[0].z  += a0.x*b.z; acc[0].w  += a0.x*b.w;
    acc[1].x  += a0.y*b.x; acc[1].y  += a0.y*b.y; acc[1].z  += a0.y*b.z; acc[1].w  += a0.y*b.w;
    acc[2].x  += a0.z*b.x; acc[2].y  += a0.z*b.y; acc[2].z  += a0.z*b.z; acc[2].w  += a0.z*b.w;
    acc[3].x  += a0.w*b.x; acc[3].y  += a0.w*b.y; acc[3].z  += a0.w*b.z; acc[3].w  += a0.w*b.w;
    acc[4].x  += a1.x*b.x; acc[4].y  += a1.x*b.y; acc[4].z  += a1.x*b.z; acc[4].w  += a1.x*b.w;
    acc[5].x  += a1.y*b.x; acc[5].y  += a1.y*b.y; acc[5].z  += a1.y*b.z; acc[5].w  += a1.y*b.w;
    acc[6].x  += a1.z*b.x; acc[6].y  += a1.z*b.y; acc[6].z  += a1.z*b.z; acc[6].w  += a1.z*b.w;
    acc[7].x  += a1.w*b.x; acc[7].y  += a1.w*b.y; acc[7].z  += a1.w*b.z; acc[7].w  += a1.w*b.w;
    acc[8].x  += a2.x*b.x; acc[8].y  += a2.x*b.y; acc[8].z  += a2.x*b.z; acc[8].w  += a2.x*b.w;
    acc[9].x  += a2.y*b.x; acc[9].y  += a2.y*b.y; acc[9].z  += a2.y*b.z; acc[9].w  += a2.y*b.w;
    acc[10].x += a2.z*b.x; acc[10].y += a2.z*b.y; acc[10].z += a2.z*b.z; acc[10].w += a2.z*b.w;
    acc[11].x += a2.w*b.x; acc[11].y += a2.w*b.y; acc[11].z += a2.w*b.z; acc[11].w += a2.w*b.w;
    acc[12].x += a3.x*b.x; acc[12].y += a3.x*b.y; acc[12].z += a3.x*b.z; acc[12].w += a3.x*b.w;
    acc[13].x += a3.y*b.x; acc[13].y += a3.y*b.y; acc[13].z += a3.y*b.z; acc[13].w += a3.y*b.w;
    acc[14].x += a3.z*b.x; acc[14].y += a3.z*b.y; acc[14].z += a3.z*b.z; acc[14].w += a3.z*b.w;
    acc[15].x += a3.w*b.x; acc[15].y += a3.w*b.y; acc[15].z += a3.w*b.z; acc[15].w += a3.w*b.w;
  }
  const bool colok = (s0 + tx * 4) < N;
  #pragma unroll
  for (int e = 0; e < 16; ++e) {
    int r = r0 + ty * 16 + e;
    if (r < N && colok) {
      float4* p = (float4*)&A[(size_t)r * N + s0 + tx * 4];
      float4 v = *p;
      v.x -= acc[e].x; v.y -= acc[e].y; v.z -= acc[e].z; v.w -= acc[e].w;
      *p = v;
    }
  }
}

// ======================= gate + top-k + effective weights =======================
__global__ void select_kernel(const void* __restrict__ flagsraw, const double* __restrict__ scores,
                              const float* __restrict__ w1, const float* __restrict__ b1,
                              const float* __restrict__ w2, const float* __restrict__ b2,
                              int* __restrict__ topidx, float* __restrict__ misc,
                              float* __restrict__ out_tail) {
  if (threadIdx.x != 0 || blockIdx.x != 0) return;
  const unsigned char* fb = (const unsigned char*)flagsraw;
  bool nonbin = false, off4 = false;
  for (int i = 0; i < 16; ++i) {
    if (fb[i] > 1) nonbin = true;
    if ((i & 3) && fb[i]) off4 = true;
  }
  int f[16]; int nact = 0;
  for (int i = 0; i < 16; ++i) {
    int v;
    if (nonbin)      v = (((const float*)flagsraw)[i] != 0.0f);
    else if (off4)   v = (fb[i] != 0);
    else             v = (((const int*)flagsraw)[i] != 0);
    f[i] = v; nact += v;
  }
  int gate = (nact >= 4) ? 1 : 0;   // THRESH = 4
  double sc[16];
  for (int i = 0; i < 16; ++i) sc[i] = f[i] ? scores[i] : -1.0e300;
  bool used[16] = {};
  for (int k = 0; k < 8; ++k) {     // descending, ties -> lowest index (lax.top_k)
    int bi = -1; double bv = 0.0;
    for (int i = 0; i < 16; ++i)
      if (!used[i] && (bi < 0 || sc[i] > bv)) { bv = sc[i]; bi = i; }
    used[bi] = true;
    topidx[k] = bi;
  }
  for (int cC = 0; cC < 10; ++cC) {
    float s = 0.0f;
    for (int h = 0; h < 32; ++h) s += w2[h] * w1[h * 10 + cC];
    misc[cC] = s;
  }
  float be = 0.0f;
  for (int h = 0; h < 32; ++h) be += w2[h] * b1[h];
  be += b2[0];
  misc[10] = be;
  ((int*)misc)[12] = gate;
  *out_tail = gate ? 1.0f : 0.0f;
}

// ======================= build combined right-hand matrices M0..M2 =======================
__global__ __launch_bounds__(256) void build_m_kernel(const float* __restrict__ x,
                                                      const int* __restrict__ topidx,
                                                      const float* __restrict__ misc,
                                                      float* __restrict__ M) {
  int i = blockIdx.x * 256 + threadIdx.x;   // 262144 float4 positions
  const float4* T1 = (const float4*)(x + (size_t)topidx[1] * NN);
  const float4* T2 = (const float4*)(x + (size_t)topidx[2] * NN);
  const float4* T3 = (const float4*)(x + (size_t)topidx[3] * NN);
  float w0 = misc[0], w1_ = misc[1], w2_ = misc[2], w3_ = misc[3], w4_ = misc[4], w5_ = misc[5];
  float4 t1 = T1[i], t2 = T2[i], t3 = T3[i];
  float4 m0, m1, m2;
  m0.x = w0 * t1.x + w1_ * t2.x + w2_ * t3.x;
  m0.y = w0 * t1.y + w1_ * t2.y + w2_ * t3.y;
  m0.z = w0 * t1.z + w1_ * t2.z + w2_ * t3.z;
  m0.w = w0 * t1.w + w1_ * t2.w + w2_ * t3.w;
  m1.x = w3_ * t2.x + w4_ * t3.x;
  m1.y = w3_ * t2.y + w4_ * t3.y;
  m1.z = w3_ * t2.z + w4_ * t3.z;
  m1.w = w3_ * t2.w + w4_ * t3.w;
  m2.x = w5_ * t3.x;  m2.y = w5_ * t3.y;  m2.z = w5_ * t3.z;  m2.w = w5_ * t3.w;
  ((float4*)M)[i] = m0;
  ((float4*)(M + NN))[i] = m1;
  ((float4*)(M + 2 * (size_t)NN))[i] = m2;
}

// ======================= split-K final GEMM: P[chunk] = A_chunk @ B_chunk ==========
// VERIFIED round-3 kernel, unchanged.
__global__ __launch_bounds__(256) void final_gemm_kernel(const float* __restrict__ x,
                                                         const float* __restrict__ M,
                                                         const int* __restrict__ topidx,
                                                         float* __restrict__ P) {
  const int chunk = blockIdx.x >> 8;   // 0..5
  const int t  = blockIdx.x & 255;
  const int tr = t >> 4, tc = t & 15;
  const int mi  = chunk >> 1;
  const int k0b = (chunk & 1) << 9;    // 0 or 512
  const float* A = x + (size_t)topidx[mi] * NN;
  const float* B = M + (size_t)mi * NN;
  __shared__ float As[32][68];   // A^T fragment: As[k][r], float4-aligned stride
  __shared__ float Bs[32][68];
  const int ty = threadIdx.x >> 4, tx = threadIdx.x & 15;
  float acc[4][4] = {};
  for (int k0 = k0b; k0 < k0b + 512; k0 += 32) {
    for (int idx = threadIdx.x; idx < 2048; idx += 256) {
      int r = idx >> 5, k = idx & 31;
      As[k][r] = A[(size_t)(tr * 64 + r) * N + k0 + k];
    }
    for (int idx = threadIdx.x; idx < 2048; idx += 256) {
      int k = idx >> 6, cc = idx & 63;
      Bs[k][cc] = B[(size_t)(k0 + k) * N + tc * 64 + cc];
    }
    __syncthreads();
    #pragma unroll 8
    for (int k = 0; k < 32; ++k) {
      float4 a = *(const float4*)&As[k][ty * 4];
      float4 b = *(const float4*)&Bs[k][tx * 4];
      acc[0][0] += a.x * b.x; acc[0][1] += a.x * b.y; acc[0][2] += a.x * b.z; acc[0][3] += a.x * b.w;
      acc[1][0] += a.y * b.x; acc[1][1] += a.y * b.y; acc[1][2] += a.y * b.z; acc[1][3] += a.y * b.w;
      acc[2][0] += a.z * b.x; acc[2][1] += a.z * b.y; acc[2][2] += a.z * b.z; acc[2][3] += a.z * b.w;
      acc[3][0] += a.w * b.x; acc[3][1] += a.w * b.y; acc[3][2] += a.w * b.z; acc[3][3] += a.w * b.w;
    }
    __syncthreads();
  }
  float* Pc = P + (size_t)chunk * NN;
  #pragma unroll
  for (int i = 0; i < 4; ++i) {
    size_t r = (size_t)(tr * 64 + ty * 4 + i);
    float4 v = make_float4(acc[i][0], acc[i][1], acc[i][2], acc[i][3]);
    *(float4*)&Pc[r * N + tc * 64 + tx * 4] = v;
  }
}

// ======================= reduce partials + preserve channels + bias ================
__global__ __launch_bounds__(256) void reduce_out_kernel(const float* __restrict__ x,
                                                         const float* __restrict__ P,
                                                         const int* __restrict__ topidx,
                                                         const float* __restrict__ misc,
                                                         float* __restrict__ out) {
  int i = blockIdx.x * 256 + threadIdx.x;   // 262144 float4 positions
  int gate = ((const int*)misc)[12];
  float4* o = (float4*)out;
  if (!gate) { o[i] = make_float4(0.f, 0.f, 0.f, 0.f); return; }
  float w6 = misc[6], w7 = misc[7], w8 = misc[8], w9 = misc[9], be = misc[10];
  float4 p0 = ((const float4*)(x + (size_t)topidx[4] * NN))[i];
  float4 p1 = ((const float4*)(x + (size_t)topidx[5] * NN))[i];
  float4 p2 = ((const float4*)(x + (size_t)topidx[6] * NN))[i];
  float4 p3 = ((const float4*)(x + (size_t)topidx[7] * NN))[i];
  float4 r;
  r.x = be + w6 * p0.x + w7 * p1.x + w8 * p2.x + w9 * p3.x;
  r.y = be + w6 * p0.y + w7 * p1.y + w8 * p2.y + w9 * p3.y;
  r.z = be + w6 * p0.z + w7 * p1.z + w8 * p2.z + w9 * p3.z;
  r.w = be + w6 * p0.w + w7 * p1.w + w8 * p2.w + w9 * p3.w;
  #pragma unroll
  for (int cN = 0; cN < 6; ++cN) {
    float4 q = ((const float4*)(P + (size_t)cN * NN))[i];
    r.x += q.x; r.y += q.y; r.z += q.z; r.w += q.w;
  }
  o[i] = r;
}

// ======================= host =======================
extern "C" void kernel_launch(void* const* d_in, const int* in_sizes, int n_in,
                              void* d_out, int out_size, void* d_ws, size_t ws_size,
                              hipStream_t stream) {
  const float* x  = (const float*)d_in[0];
  const void*  fl = d_in[1];
  const float* w1 = (const float*)d_in[2];
  const float* b1 = (const float*)d_in[3];
  const float* w2 = (const float*)d_in[4];
  const float* b2 = (const float*)d_in[5];
  float* out = (float*)d_out;

  char* ws = (char*)d_ws;
  float* LU = (float*)ws;                                // 64 MB (dead after LU phase)
  float* Mm = (float*)ws;                                // 12 MB, reuses LU space
  float* P  = (float*)(ws + (size_t)12 * 1024 * 1024);   // 24 MB partials, inside old LU
  size_t tail = (size_t)16 * NN * sizeof(float);         // 67,108,864
  double* scores = (double*)(ws + tail);                 // 16 doubles
  int*    ipiv   = (int*)(ws + tail + 256);              // 16*32 ints
  int*    topidx = (int*)(ws + tail + 256 + 2304);       // 8 ints
  float*  misc   = (float*)(ws + tail + 256 + 2304 + 256); // weff[10], beff, gate

  init_kernel<<<1, 64, 0, stream>>>(scores);
  copy_kernel<<<16384, 256, 0, stream>>>((const float4*)x, (float4*)LU);

  for (int c0 = 0; c0 < N; c0 += 32) {
    panel_kernel<<<16, 64, 0, stream>>>(LU, ipiv, scores, c0);
    int tcols = N - c0 - 32;
    if (tcols > 0) {
      int ncs = (tcols + 255) / 256;
      ptrsm_kernel<<<16 * ncs, 256, 0, stream>>>(LU, ipiv, c0, ncs);
      int nrt = (tcols + 63) / 64;
      update_kernel<<<16 * nrt * ncs, 256, 0, stream>>>(LU, c0, nrt, ncs);
    }
  }

  select_kernel<<<1, 64, 0, stream>>>(fl, scores, w1, b1, w2, b2, topidx, misc, out + NN);
  build_m_kernel<<<1024, 256, 0, stream>>>(x, topidx, misc, Mm);
  final_gemm_kernel<<<1536, 256, 0, stream>>>(x, Mm, topidx, P);
  reduce_out_kernel<<<1024, 256, 0, stream>>>(x, P, topidx, misc, out);
}

// Round 9
// 4330.003 us; speedup vs baseline: 1.6437x; 1.1635x over previous
//
#include <hip/hip_runtime.h>
#include <math.h>

#define N 1024
#define NN (N*N)
#define PST 36   // panel row stride in floats: 144B = 16B-aligned, 2x-min bank tiling

// ======================= init =======================
__global__ void init_kernel(double* scores) {
  int t = threadIdx.x;
  if (t < 16) scores[t] = 0.0;
}

// ======================= copy x -> LU workspace =======================
__global__ __launch_bounds__(256) void copy_kernel(const float4* __restrict__ src,
                                                   float4* __restrict__ dst) {
  int i = blockIdx.x * 256 + threadIdx.x;   // grid sized exactly: 16M floats / 4
  dst[i] = src[i];
}

// ======================= LU panel (width 32): 4 waves, LDS rows, small code =====
// 256 threads / 4 waves per matrix. Rows in LDS (stride PST); lane owns rows
// tid, tid+256, tid+512, tid+768. Physical LDS row swaps (lanes 0..7, b128) =
// exact LAPACK pivot semantics (argmax |col j|, tie -> min row; ipiv = c0+pcur),
// identical to verified R8. j-loop NOT unrolled (code stays ~2KB, fits L1I);
// per-element position handled by wave-uniform branches on ej=j&3. U-row chunks
// hoisted to 8 static registers per step. Reduction: intra-lane over 4 rows ->
// 64-lane shfl butterfly -> 4-entry LDS tree combined redundantly by all
// threads. 2 barriers/step over 4 waves.
__global__ __launch_bounds__(256, 1) void panel_kernel(float* __restrict__ lu,
                                                       int* __restrict__ ipiv,
                                                       double* __restrict__ scores,
                                                       int c0) {
  __shared__ __align__(16) float sh[1024 * PST];   // 147,456 B
  __shared__ float ujjS[32];
  __shared__ float redv[4];
  __shared__ int   redk[4];
  const int m = blockIdx.x;
  float* A = lu + (size_t)m * NN;
  const int R = N - c0;
  const int tid = threadIdx.x;

  // ---- load panel rows (cols c0..c0+31 are 16B aligned; c0 % 32 == 0) ----
  for (int idx = tid; idx < (R << 3); idx += 256) {
    int r = idx >> 3, q = idx & 7;
    *(float4*)&sh[r * PST + 4 * q] =
        *(const float4*)(A + (size_t)(c0 + r) * N + c0 + 4 * q);
  }
  __syncthreads();

  // ---- prescan: pivot for column 0 ----
  int pcur;
  {
    float bval = -1.0f; int brow = 0x7fffffff;
    #pragma unroll
    for (int t4 = 0; t4 < 4; ++t4) {
      int r = tid + (t4 << 8);
      if (r < R) {
        float v = fabsf(sh[r * PST]);
        if (v > bval || (v == bval && r < brow)) { bval = v; brow = r; }
      }
    }
    #pragma unroll
    for (int mask = 32; mask; mask >>= 1) {
      float ov = __shfl_xor(bval, mask);
      int   orr = __shfl_xor(brow, mask);
      if (ov > bval || (ov == bval && orr < brow)) { bval = ov; brow = orr; }
    }
    if ((tid & 63) == 0) { redv[tid >> 6] = bval; redk[tid >> 6] = brow; }
    __syncthreads();
    float bv = redv[0]; int bk = redk[0];
    float v1 = redv[1]; int k1 = redk[1];
    float v2 = redv[2]; int k2 = redk[2];
    float v3 = redv[3]; int k3 = redk[3];
    if (v1 > bv || (v1 == bv && k1 < bk)) { bv = v1; bk = k1; }
    if (v2 > bv || (v2 == bv && k2 < bk)) { bv = v2; bk = k2; }
    if (v3 > bv || (v3 == bv && k3 < bk)) { bv = v3; bk = k3; }
    pcur = bk;
  }
  __syncthreads();   // protect redv/redk reads before step-0 rewrite

  #pragma unroll 1
  for (int j = 0; j < 32; ++j) {
    // ---- swap rows j <-> pcur in LDS (lanes 0..7, full 32-col rows) ----
    if (pcur != j && tid < 8) {
      float4 a = *(float4*)&sh[j * PST + 4 * tid];
      float4 b = *(float4*)&sh[pcur * PST + 4 * tid];
      *(float4*)&sh[j * PST + 4 * tid] = b;
      *(float4*)&sh[pcur * PST + 4 * tid] = a;
    }
    if (tid == 0) ipiv[m * 32 + j] = c0 + pcur;
    __syncthreads();   // B1: swap visible

    const int qj = j >> 2, ej = j & 3;
    const int jn = j + 1;
    const int qn = (j < 31) ? (jn >> 2) : -1, en = jn & 3;
    const float ujj = sh[j * PST + j];
    if (tid == 0) ujjS[j] = ujj;
    const float rujj = 1.0f / ujj;

    // U-row chunks -> static registers (broadcast b128 reads)
    float4 u4[8];
    #pragma unroll
    for (int q = 0; q < 8; ++q)
      if (4 * q + 3 >= j) u4[q] = *(const float4*)&sh[j * PST + 4 * q];

    // ---- update owned rows r > j; fused scan of column j+1 ----
    float bval = -1.0f; int brow = 0x7fffffff;
    #pragma unroll
    for (int t4 = 0; t4 < 4; ++t4) {
      int r = tid + (t4 << 8);
      if (r > j && r < R) {
        float* rp = &sh[r * PST];
        float l = 0.0f, nv = 0.0f;
        #pragma unroll
        for (int q = 0; q < 8; ++q) {
          if (q < qj) continue;                  // uniform runtime guard
          float4 v = *(float4*)&rp[4 * q];
          if (q == qj) {
            float aj = (ej == 0) ? v.x : (ej == 1) ? v.y : (ej == 2) ? v.z : v.w;
            l = aj * rujj;
            if (ej == 0)      { v.x = l; v.y -= l * u4[q].y; v.z -= l * u4[q].z; v.w -= l * u4[q].w; }
            else if (ej == 1) { v.y = l; v.z -= l * u4[q].z; v.w -= l * u4[q].w; }
            else if (ej == 2) { v.z = l; v.w -= l * u4[q].w; }
            else              { v.w = l; }
          } else {
            v.x -= l * u4[q].x; v.y -= l * u4[q].y;
            v.z -= l * u4[q].z; v.w -= l * u4[q].w;
          }
          if (q == qn)
            nv = (en == 0) ? v.x : (en == 1) ? v.y : (en == 2) ? v.z : v.w;
          *(float4*)&rp[4 * q] = v;
        }
        if (j < 31) {
          float av = fabsf(nv);
          if (av > bval || (av == bval && r < brow)) { bval = av; brow = r; }
        }
      }
    }
    if (j < 31) {
      #pragma unroll
      for (int mask = 32; mask; mask >>= 1) {
        float ov = __shfl_xor(bval, mask);
        int   orr = __shfl_xor(brow, mask);
        if (ov > bval || (ov == bval && orr < brow)) { bval = ov; brow = orr; }
      }
      if ((tid & 63) == 0) { redv[tid >> 6] = bval; redk[tid >> 6] = brow; }
    }
    __syncthreads();   // B2: updates + redv/redk visible
    if (j < 31) {
      float bv = redv[0]; int bk = redk[0];
      float v1 = redv[1]; int k1 = redk[1];
      float v2 = redv[2]; int k2 = redk[2];
      float v3 = redv[3]; int k3 = redk[3];
      if (v1 > bv || (v1 == bv && k1 < bk)) { bv = v1; bk = k1; }
      if (v2 > bv || (v2 == bv && k2 < bk)) { bv = v2; bk = k2; }
      if (v3 > bv || (v3 == bv && k3 < bk)) { bv = v3; bk = k3; }
      pcur = bk;
    }
  }

  // ---- writeback ----
  for (int idx = tid; idx < (R << 3); idx += 256) {
    int r = idx >> 3, q = idx & 7;
    *(float4*)(A + (size_t)(c0 + r) * N + c0 + 4 * q) =
        *(const float4*)&sh[r * PST + 4 * q];
  }
  // ---- logsum: lane-parallel logs + shfl-reduce (wave 0) ----
  if (tid < 64) {
    double lg = 0.0;
    if (tid < 32) lg = log(fabs((double)ujjS[tid]));
    #pragma unroll
    for (int mask = 32; mask; mask >>= 1) lg += __shfl_xor(lg, mask);
    if (tid == 0) atomicAdd(&scores[m], lg);
  }
}

// ======================= permutation-gather + TRSM =======================
// VERIFIED round-6 kernel, unchanged.
__global__ __launch_bounds__(256) void ptrsm_kernel(float* __restrict__ lu,
                                                    const int* __restrict__ ipiv,
                                                    int c0, int ncs) {
  const int m  = blockIdx.x / ncs;
  const int cs = blockIdx.x % ncs;
  const int s0 = c0 + 32 + cs * 256;
  const int tid = threadIdx.x;
  const int col = s0 + tid;
  const bool ac = col < N;
  float* A = lu + (size_t)m * NN;
  const int R = N - c0;
  __shared__ int   rowAt[1024];     // content map over rows [c0, N)
  __shared__ float L11s[32][33];
  __shared__ int   dDst[48];
  __shared__ int   dSrc[48];
  __shared__ int   dcount;

  for (int r = tid; r < R; r += 256) rowAt[r] = c0 + r;
  if (tid == 0) dcount = 0;
  for (int idx = tid; idx < 1024; idx += 256) {
    int i = idx >> 5, k = idx & 31;
    L11s[i][k] = A[(size_t)(c0 + i) * N + c0 + k];
  }
  __syncthreads();
  if (tid == 0) {
    #pragma unroll 1
    for (int j = 0; j < 32; ++j) {
      int p = ipiv[m * 32 + j];
      if (p != c0 + j) { int t = rowAt[j]; rowAt[j] = rowAt[p - c0]; rowAt[p - c0] = t; }
    }
  }
  __syncthreads();
  // collect displaced A22 rows (dst receives content of src)
  for (int r = 32 + tid; r < R; r += 256) {
    if (rowAt[r] != c0 + r) {
      int i = atomicAdd(&dcount, 1);
      dDst[i] = c0 + r; dSrc[i] = rowAt[r];
    }
  }
  __syncthreads();
  const int nd = dcount;   // <= 32

  // ---- read phase (all loads before any store) ----
  float pay[32];
  #pragma unroll
  for (int i = 0; i < 32; ++i)
    if (i < nd && ac) pay[i] = A[(size_t)dSrc[i] * N + col];
  float u[32];
  #pragma unroll
  for (int i = 0; i < 32; ++i)
    if (ac) u[i] = A[(size_t)rowAt[i] * N + col];

  // ---- TRSM: u = L11^{-1} a12 (unit diag) ----
  #pragma unroll
  for (int i = 1; i < 32; ++i) {
    float a = u[i];
    #pragma unroll
    for (int k = 0; k < 32; ++k)
      if (k < i) a -= L11s[i][k] * u[k];
    u[i] = a;
  }

  // ---- write phase ----
  #pragma unroll
  for (int i = 0; i < 32; ++i)
    if (i < nd && ac) A[(size_t)dDst[i] * N + col] = pay[i];
  #pragma unroll
  for (int i = 0; i < 32; ++i)
    if (ac) A[(size_t)(c0 + i) * N + col] = u[i];
}

// ======================= trailing update: A22 -= L21 @ U12 (K=32) ================
// VERIFIED round-6 kernel, unchanged.
__global__ __launch_bounds__(256) void update_kernel(float* __restrict__ lu,
                                                     int c0, int nrt, int ncs) {
  const int per = nrt * ncs;
  const int m  = blockIdx.x / per;
  const int t  = blockIdx.x % per;
  const int rt = t / ncs, cs = t % ncs;
  const int r0 = c0 + 32 + rt * 64;
  const int s0 = c0 + 32 + cs * 256;
  const int tid = threadIdx.x;
  float* A = lu + (size_t)m * NN;
  __shared__ float Lts[32][68];    // L21 tile transposed: [k][r]
  __shared__ float Us[32][260];    // U12 stripe: [k][c]
  for (int idx = tid; idx < 2048; idx += 256) {
    int r = idx >> 5, k = idx & 31;
    Lts[k][r] = (r0 + r < N) ? A[(size_t)(r0 + r) * N + c0 + k] : 0.0f;
  }
  for (int idx = tid; idx < 8192; idx += 256) {
    int k = idx >> 8, c = idx & 255;
    Us[k][c] = (s0 + c < N) ? A[(size_t)(c0 + k) * N + s0 + c] : 0.0f;
  }
  __syncthreads();
  const int tx = tid & 63;    // col group: 4 cols
  const int ty = tid >> 6;    // row group: 16 rows (== wave id -> uniform a-reads)
  float4 acc[16];
  #pragma unroll
  for (int e = 0; e < 16; ++e) acc[e] = make_float4(0.f, 0.f, 0.f, 0.f);
  #pragma unroll 4
  for (int k = 0; k < 32; ++k) {
    float4 b  = *(const float4*)&Us[k][tx * 4];
    float4 a0 = *(const float4*)&Lts[k][ty * 16 + 0];
    float4 a1 = *(const float4*)&Lts[k][ty * 16 + 4];
    float4 a2 = *(const float4*)&Lts[k][ty * 16 + 8];
    float4 a3 = *(const float4*)&Lts[k][ty * 16 + 12];
    acc[0].x  += a0.x*b.x; acc[0].y  += a0.x*b.y; acc[0].z  += a0.x*b.z; acc[0].w  += a0.x*b.w;
    acc[1].x  += a0.y*b.x; acc[1].y  += a0.y*b.y; acc[1].z  += a0.y*b.z; acc[1].w  += a0.y*b.w;
    acc[2].x  += a0.z*b.x; acc[2].y  += a0.z*b.y; acc[2].z  += a0.z*b.z; acc[2].w  += a0.z*b.w;
    acc[3].x  += a0.w*b.x; acc[3].y  += a0.w*b.y; acc[3].z  += a0.w*b.z; acc[3].w  += a0.w*b.w;
    acc[4].x  += a1.x*b.x; acc[4].y  += a1.x*b.y; acc[4].z  += a1.x*b.z; acc[4].w  += a1.x*b.w;
    acc[5].x  += a1.y*b.x; acc[5].y  += a1.y*b.y; acc[5].z  += a1.y*b.z; acc[5].w  += a1.y*b.w;
    acc[6].x  += a1.z*b.x; acc[6].y  += a1.z*b.y; acc[6].z  += a1.z*b.z; acc[6].w  += a1.z*b.w;
    acc[7].x  += a1.w*b.x; acc[7].y  += a1.w*b.y; acc[7].z  += a1.w*b.z; acc[7].w  += a1.w*b.w;
    acc[8].x  += a2.x*b.x; acc[8].y  += a2.x*b.y; acc[8].z  += a2.x*b.z; acc[8].w  += a2.x*b.w;
    acc[9].x  += a2.y*b.x; acc[9].y  += a2.y*b.y; acc[9].z  += a2.y*b.z; acc[9].w  += a2.y*b.w;
    acc[10].x += a2.z*b.x; acc[10].y += a2.z*b.y; acc[10].z += a2.z*b.z; acc[10].w += a2.z*b.w;
    acc[11].x += a2.w*b.x; acc[11].y += a2.w*b.y; acc[11].z += a2.w*b.z; acc[11].w += a2.w*b.w;
    acc[12].x += a3.x*b.x; acc[12].y += a3.x*b.y; acc[12].z += a3.x*b.z; acc[12].w += a3.x*b.w;
    acc[13].x += a3.y*b.x; acc[13].y += a3.y*b.y; acc[13].z += a3.y*b.z; acc[13].w += a3.y*b.w;
    acc[14].x += a3.z*b.x; acc[14].y += a3.z*b.y; acc[14].z += a3.z*b.z; acc[14].w += a3.z*b.w;
    acc[15].x += a3.w*b.x; acc[15].y += a3.w*b.y; acc[15].z += a3.w*b.z; acc[15].w += a3.w*b.w;
  }
  const bool colok = (s0 + tx * 4) < N;
  #pragma unroll
  for (int e = 0; e < 16; ++e) {
    int r = r0 + ty * 16 + e;
    if (r < N && colok) {
      float4* p = (float4*)&A[(size_t)r * N + s0 + tx * 4];
      float4 v = *p;
      v.x -= acc[e].x; v.y -= acc[e].y; v.z -= acc[e].z; v.w -= acc[e].w;
      *p = v;
    }
  }
}

// ======================= gate + top-k + effective weights =======================
__global__ void select_kernel(const void* __restrict__ flagsraw, const double* __restrict__ scores,
                              const float* __restrict__ w1, const float* __restrict__ b1,
                              const float* __restrict__ w2, const float* __restrict__ b2,
                              int* __restrict__ topidx, float* __restrict__ misc,
                              float* __restrict__ out_tail) {
  if (threadIdx.x != 0 || blockIdx.x != 0) return;
  const unsigned char* fb = (const unsigned char*)flagsraw;
  bool nonbin = false, off4 = false;
  for (int i = 0; i < 16; ++i) {
    if (fb[i] > 1) nonbin = true;
    if ((i & 3) && fb[i]) off4 = true;
  }
  int f[16]; int nact = 0;
  for (int i = 0; i < 16; ++i) {
    int v;
    if (nonbin)      v = (((const float*)flagsraw)[i] != 0.0f);
    else if (off4)   v = (fb[i] != 0);
    else             v = (((const int*)flagsraw)[i] != 0);
    f[i] = v; nact += v;
  }
  int gate = (nact >= 4) ? 1 : 0;   // THRESH = 4
  double sc[16];
  for (int i = 0; i < 16; ++i) sc[i] = f[i] ? scores[i] : -1.0e300;
  bool used[16] = {};
  for (int k = 0; k < 8; ++k) {     // descending, ties -> lowest index (lax.top_k)
    int bi = -1; double bv = 0.0;
    for (int i = 0; i < 16; ++i)
      if (!used[i] && (bi < 0 || sc[i] > bv)) { bv = sc[i]; bi = i; }
    used[bi] = true;
    topidx[k] = bi;
  }
  for (int cC = 0; cC < 10; ++cC) {
    float s = 0.0f;
    for (int h = 0; h < 32; ++h) s += w2[h] * w1[h * 10 + cC];
    misc[cC] = s;
  }
  float be = 0.0f;
  for (int h = 0; h < 32; ++h) be += w2[h] * b1[h];
  be += b2[0];
  misc[10] = be;
  ((int*)misc)[12] = gate;
  *out_tail = gate ? 1.0f : 0.0f;
}

// ======================= build combined right-hand matrices M0..M2 =======================
__global__ __launch_bounds__(256) void build_m_kernel(const float* __restrict__ x,
                                                      const int* __restrict__ topidx,
                                                      const float* __restrict__ misc,
                                                      float* __restrict__ M) {
  int i = blockIdx.x * 256 + threadIdx.x;   // 262144 float4 positions
  const float4* T1 = (const float4*)(x + (size_t)topidx[1] * NN);
  const float4* T2 = (const float4*)(x + (size_t)topidx[2] * NN);
  const float4* T3 = (const float4*)(x + (size_t)topidx[3] * NN);
  float w0 = misc[0], w1_ = misc[1], w2_ = misc[2], w3_ = misc[3], w4_ = misc[4], w5_ = misc[5];
  float4 t1 = T1[i], t2 = T2[i], t3 = T3[i];
  float4 m0, m1, m2;
  m0.x = w0 * t1.x + w1_ * t2.x + w2_ * t3.x;
  m0.y = w0 * t1.y + w1_ * t2.y + w2_ * t3.y;
  m0.z = w0 * t1.z + w1_ * t2.z + w2_ * t3.z;
  m0.w = w0 * t1.w + w1_ * t2.w + w2_ * t3.w;
  m1.x = w3_ * t2.x + w4_ * t3.x;
  m1.y = w3_ * t2.y + w4_ * t3.y;
  m1.z = w3_ * t2.z + w4_ * t3.z;
  m1.w = w3_ * t2.w + w4_ * t3.w;
  m2.x = w5_ * t3.x;  m2.y = w5_ * t3.y;  m2.z = w5_ * t3.z;  m2.w = w5_ * t3.w;
  ((float4*)M)[i] = m0;
  ((float4*)(M + NN))[i] = m1;
  ((float4*)(M + 2 * (size_t)NN))[i] = m2;
}

// ======================= split-K final GEMM: P[chunk] = A_chunk @ B_chunk ==========
// VERIFIED round-3 kernel, unchanged.
__global__ __launch_bounds__(256) void final_gemm_kernel(const float* __restrict__ x,
                                                         const float* __restrict__ M,
                                                         const int* __restrict__ topidx,
                                                         float* __restrict__ P) {
  const int chunk = blockIdx.x >> 8;   // 0..5
  const int t  = blockIdx.x & 255;
  const int tr = t >> 4, tc = t & 15;
  const int mi  = chunk >> 1;
  const int k0b = (chunk & 1) << 9;    // 0 or 512
  const float* A = x + (size_t)topidx[mi] * NN;
  const float* B = M + (size_t)mi * NN;
  __shared__ float As[32][68];   // A^T fragment: As[k][r], float4-aligned stride
  __shared__ float Bs[32][68];
  const int ty = threadIdx.x >> 4, tx = threadIdx.x & 15;
  float acc[4][4] = {};
  for (int k0 = k0b; k0 < k0b + 512; k0 += 32) {
    for (int idx = threadIdx.x; idx < 2048; idx += 256) {
      int r = idx >> 5, k = idx & 31;
      As[k][r] = A[(size_t)(tr * 64 + r) * N + k0 + k];
    }
    for (int idx = threadIdx.x; idx < 2048; idx += 256) {
      int k = idx >> 6, cc = idx & 63;
      Bs[k][cc] = B[(size_t)(k0 + k) * N + tc * 64 + cc];
    }
    __syncthreads();
    #pragma unroll 8
    for (int k = 0; k < 32; ++k) {
      float4 a = *(const float4*)&As[k][ty * 4];
      float4 b = *(const float4*)&Bs[k][tx * 4];
      acc[0][0] += a.x * b.x; acc[0][1] += a.x * b.y; acc[0][2] += a.x * b.z; acc[0][3] += a.x * b.w;
      acc[1][0] += a.y * b.x; acc[1][1] += a.y * b.y; acc[1][2] += a.y * b.z; acc[1][3] += a.y * b.w;
      acc[2][0] += a.z * b.x; acc[2][1] += a.z * b.y; acc[2][2] += a.z * b.z; acc[2][3] += a.z * b.w;
      acc[3][0] += a.w * b.x; acc[3][1] += a.w * b.y; acc[3][2] += a.w * b.z; acc[3][3] += a.w * b.w;
    }
    __syncthreads();
  }
  float* Pc = P + (size_t)chunk * NN;
  #pragma unroll
  for (int i = 0; i < 4; ++i) {
    size_t r = (size_t)(tr * 64 + ty * 4 + i);
    float4 v = make_float4(acc[i][0], acc[i][1], acc[i][2], acc[i][3]);
    *(float4*)&Pc[r * N + tc * 64 + tx * 4] = v;
  }
}

// ======================= reduce partials + preserve channels + bias ================
__global__ __launch_bounds__(256) void reduce_out_kernel(const float* __restrict__ x,
                                                         const float* __restrict__ P,
                                                         const int* __restrict__ topidx,
                                                         const float* __restrict__ misc,
                                                         float* __restrict__ out) {
  int i = blockIdx.x * 256 + threadIdx.x;   // 262144 float4 positions
  int gate = ((const int*)misc)[12];
  float4* o = (float4*)out;
  if (!gate) { o[i] = make_float4(0.f, 0.f, 0.f, 0.f); return; }
  float w6 = misc[6], w7 = misc[7], w8 = misc[8], w9 = misc[9], be = misc[10];
  float4 p0 = ((const float4*)(x + (size_t)topidx[4] * NN))[i];
  float4 p1 = ((const float4*)(x + (size_t)topidx[5] * NN))[i];
  float4 p2 = ((const float4*)(x + (size_t)topidx[6] * NN))[i];
  float4 p3 = ((const float4*)(x + (size_t)topidx[7] * NN))[i];
  float4 r;
  r.x = be + w6 * p0.x + w7 * p1.x + w8 * p2.x + w9 * p3.x;
  r.y = be + w6 * p0.y + w7 * p1.y + w8 * p2.y + w9 * p3.y;
  r.z = be + w6 * p0.z + w7 * p1.z + w8 * p2.z + w9 * p3.z;
  r.w = be + w6 * p0.w + w7 * p1.w + w8 * p2.w + w9 * p3.w;
  #pragma unroll
  for (int cN = 0; cN < 6; ++cN) {
    float4 q = ((const float4*)(P + (size_t)cN * NN))[i];
    r.x += q.x; r.y += q.y; r.z += q.z; r.w += q.w;
  }
  o[i] = r;
}

// ======================= host =======================
extern "C" void kernel_launch(void* const* d_in, const int* in_sizes, int n_in,
                              void* d_out, int out_size, void* d_ws, size_t ws_size,
                              hipStream_t stream) {
  const float* x  = (const float*)d_in[0];
  const void*  fl = d_in[1];
  const float* w1 = (const float*)d_in[2];
  const float* b1 = (const float*)d_in[3];
  const float* w2 = (const float*)d_in[4];
  const float* b2 = (const float*)d_in[5];
  float* out = (float*)d_out;

  char* ws = (char*)d_ws;
  float* LU = (float*)ws;                                // 64 MB (dead after LU phase)
  float* Mm = (float*)ws;                                // 12 MB, reuses LU space
  float* P  = (float*)(ws + (size_t)12 * 1024 * 1024);   // 24 MB partials, inside old LU
  size_t tail = (size_t)16 * NN * sizeof(float);         // 67,108,864
  double* scores = (double*)(ws + tail);                 // 16 doubles
  int*    ipiv   = (int*)(ws + tail + 256);              // 16*32 ints
  int*    topidx = (int*)(ws + tail + 256 + 2304);       // 8 ints
  float*  misc   = (float*)(ws + tail + 256 + 2304 + 256); // weff[10], beff, gate

  init_kernel<<<1, 64, 0, stream>>>(scores);
  copy_kernel<<<16384, 256, 0, stream>>>((const float4*)x, (float4*)LU);

  for (int c0 = 0; c0 < N; c0 += 32) {
    panel_kernel<<<16, 256, 0, stream>>>(LU, ipiv, scores, c0);
    int tcols = N - c0 - 32;
    if (tcols > 0) {
      int ncs = (tcols + 255) / 256;
      ptrsm_kernel<<<16 * ncs, 256, 0, stream>>>(LU, ipiv, c0, ncs);
      int nrt = (tcols + 63) / 64;
      update_kernel<<<16 * nrt * ncs, 256, 0, stream>>>(LU, c0, nrt, ncs);
    }
  }

  select_kernel<<<1, 64, 0, stream>>>(fl, scores, w1, b1, w2, b2, topidx, misc, out + NN);
  build_m_kernel<<<1024, 256, 0, stream>>>(x, topidx, misc, Mm);
  final_gemm_kernel<<<1536, 256, 0, stream>>>(x, Mm, topidx, P);
  reduce_out_kernel<<<1024, 256, 0, stream>>>(x, P, topidx, misc, out);
}